// Round 7
// baseline (1485.634 us; speedup 1.0000x reference)
//
#include <hip/hip_runtime.h>
#include <math.h>

typedef unsigned short u16;
typedef short bf16x8 __attribute__((ext_vector_type(8)));
typedef float f32x16 __attribute__((ext_vector_type(16)));

#define NN 20000
#define PP 3
#define TLP 10
#define TNS 20
#define DD 128
#define EE 640000

__device__ __forceinline__ float bf2f(u16 u) {
  union { unsigned u; float f; } v; v.u = ((unsigned)u) << 16; return v.f;
}
__device__ __forceinline__ u16 f2bf(float f) {
  union { float f; unsigned u; } v; v.f = f;
  unsigned r = v.u + 0x7fffu + ((v.u >> 16) & 1u);
  return (u16)(r >> 16);
}
__device__ __forceinline__ float fsig(float x) {
  return __fdividef(1.f, 1.f + __expf(-x));
}
__device__ __forceinline__ float ftanh(float x) {
  // tanh(x) = 2*sigmoid(2x) - 1; saturates correctly at +/-inf
  return fmaf(2.f, __fdividef(1.f, 1.f + __expf(-2.f * x)), -1.f);
}
__device__ __forceinline__ float loadf(const void* p, size_t i, int isf) {
  return isf ? ((const float*)p)[i] : bf2f(((const u16*)p)[i]);
}

// ------------------------------------------------------------- dtype detect
__global__ void k_detect(const void* probe, int* flag) {
  __shared__ int any;
  if (threadIdx.x == 0) any = 0;
  __syncthreads();
  const u16* p = (const u16*)probe;
  int bad = 0;
  for (int i = threadIdx.x; i < 4096; i += 256) {
    int e = (p[2 * i] >> 7) & 0xFF;
    if (e >= 0x9F) bad = 1;
  }
  if (bad) atomicOr(&any, 1);
  __syncthreads();
  if (threadIdx.x == 0) flag[0] = any;  // 1 = f32, 0 = bf16
}

// ------------------------------------------------------------- converters
struct CvtJobs {
  const void* src[16];
  int off[16];
  int n[16];
};

__global__ void k_cvt_batch(CvtJobs jobs, float* dst, const int* flag) {
  const int isf = flag[0];
  const void* s = jobs.src[blockIdx.x];
  float* d = dst + jobs.off[blockIdx.x];
  const int n = jobs.n[blockIdx.x];
  for (int i = threadIdx.x; i < n; i += 256) d[i] = loadf(s, i, isf);
}

struct CvtJobsB {
  const void* src[12];
  int off[12];
  int n[12];
};

__global__ void k_cvtb(CvtJobsB j, u16* __restrict__ dst, const int* flag) {
  const int isf = flag[0];
  const int job = blockIdx.x >> 6;
  const int chunk = blockIdx.x & 63;
  const void* s = j.src[job];
  u16* d = dst + j.off[job];
  const int n = j.n[job];
  for (int i = chunk * 256 + threadIdx.x; i < n; i += 64 * 256)
    d[i] = f2bf(loadf(s, i, isf));
}

// ------------------------------------------------------------- length sort
// counting sort of sequences by length; mode 0: LP (sg=p*N+i -> row i*P+p)
__global__ void k_lenhist(const int* __restrict__ lens, int* __restrict__ bins,
                          int numSeq, int mode) {
  int sg = blockIdx.x * 256 + threadIdx.x;
  if (sg >= numSeq) return;
  int row = (mode == 0) ? ((sg % NN) * PP + sg / NN) : sg;
  atomicAdd(&bins[lens[row]], 1);
}

__global__ void k_binscan(const int* __restrict__ bins, int* __restrict__ cursor,
                          int nb) {
  if (threadIdx.x == 0) {
    int acc = 0;
    for (int k = 0; k < nb; ++k) { cursor[k] = acc; acc += bins[k]; }
  }
}

__global__ void k_lenfill(const int* __restrict__ lens, int* __restrict__ cursor,
                          int* __restrict__ perm, int numSeq, int mode) {
  int sg = blockIdx.x * 256 + threadIdx.x;
  if (sg >= numSeq) return;
  int row = (mode == 0) ? ((sg % NN) * PP + sg / NN) : sg;
  int p = atomicAdd(&cursor[lens[row]], 1);
  perm[p] = sg;
}

// ---------------------------------------------------------------- GRU (merged, sorted)
// 512 thr = 8 waves, 32 seqs/block (length-sorted via perm -> per-block Tb).
// Waves 0-3: X producers (Wih frags), 2-slot xp ring; waves 4-7: H consumers
// (Whh frags), f32 h state in C-layout regs, Hbf double-buffered, 1 barrier/step.
__global__ __launch_bounds__(512, 2) void k_gru4(
    const int* __restrict__ permLP, const int* __restrict__ permNS, int nbLP,
    const u16* __restrict__ embLP, const u16* __restrict__ embNS,
    const int* __restrict__ idxLP, const int* __restrict__ idxNS,
    const int* __restrict__ lenLP, const int* __restrict__ lenNS,
    const u16* __restrict__ WihLP, const u16* __restrict__ WhhLP,
    const u16* __restrict__ WihNS, const u16* __restrict__ WhhNS,
    const float* __restrict__ bihLP, const float* __restrict__ bhhLP,
    const float* __restrict__ bihNS, const float* __restrict__ bhhNS,
    u16* __restrict__ HoutLP, u16* __restrict__ HoutNS) {
  __shared__ float xp[2][3][4][32][33];
  __shared__ u16 Hbf[2][4096];
  __shared__ int ivs[TNS][32];
  __shared__ int rowv[32], outv[32], lenv_s[32];
  __shared__ int Tbs;

  const int isLP = (blockIdx.x < nbLP);
  const int* perm = isLP ? (permLP + blockIdx.x * 32)
                         : (permNS + (blockIdx.x - nbLP) * 32);
  const u16* embbf = isLP ? embLP : embNS;
  const int* idx = isLP ? idxLP : idxNS;
  const int* lens = isLP ? lenLP : lenNS;
  const u16* Wih = isLP ? WihLP : WihNS;
  const u16* Whh = isLP ? WhhLP : WhhNS;
  const float* bih = isLP ? bihLP : bihNS;
  const float* bhh = isLP ? bhhLP : bhhNS;
  u16* Hout = isLP ? HoutLP : HoutNS;
  const int T = isLP ? TLP : TNS;

  const int tid = threadIdx.x;
  const int w = tid >> 6, lane = tid & 63;
  const int l31 = lane & 31, lh = lane >> 5;
  const int role = w >> 2;  // 0 = X producer, 1 = H consumer
  const int j = w & 3;
  const int d = 32 * j + l31;

  if (tid < 32) {
    int sg = perm[tid];
    int row = isLP ? ((sg % NN) * PP + sg / NN) : sg;
    rowv[tid] = row;
    outv[tid] = sg;
    lenv_s[tid] = lens[row];
  }
  __syncthreads();
  if (tid == 0) {
    int m = 1;
    for (int k = 0; k < 32; ++k) m = max(m, lenv_s[k]);
    Tbs = m;
  }
  __syncthreads();
  const int Tb = Tbs;

  for (int z = tid; z < Tb * 32; z += 512) {
    int s = z & 31, t = z >> 5;
    ivs[t][s] = idx[(size_t)rowv[s] * T + t];
  }
  ((bf16x8*)Hbf[0])[tid] = (bf16x8)(short)0;

  bf16x8 wf[24];
  {
    const u16* Ws = role ? Whh : Wih;
#pragma unroll
    for (int g = 0; g < 3; ++g)
#pragma unroll
      for (int kb = 0; kb < 8; ++kb)
        wf[g * 8 + kb] =
            *(const bf16x8*)(Ws + (size_t)(128 * g + d) * 128 + kb * 16 + lh * 8);
  }
  const float bsr = bih[d] + bhh[d];
  const float bsz = bih[128 + d] + bhh[128 + d];
  const float bin = bih[256 + d];
  const float bhn = bhh[256 + d];

  __syncthreads();
  int lenr[16];
#pragma unroll
  for (int rg = 0; rg < 16; ++rg)
    lenr[rg] = lenv_s[(rg & 3) + 8 * (rg >> 2) + 4 * lh];

  float h[16];
#pragma unroll
  for (int rg = 0; rg < 16; ++rg) h[rg] = 0.f;

  for (int i = 0; i <= Tb; ++i) {
    if (!role) {
      if (i < Tb) {
        bf16x8 Xf[8];
        const u16* erow = embbf + (size_t)ivs[i][l31] * 128 + lh * 8;
#pragma unroll
        for (int kb = 0; kb < 8; ++kb) Xf[kb] = *(const bf16x8*)(erow + kb * 16);
        f32x16 a0 = (f32x16)(0.f), a1 = (f32x16)(0.f), a2 = (f32x16)(0.f);
#pragma unroll
        for (int kb = 0; kb < 8; ++kb) {
          a0 = __builtin_amdgcn_mfma_f32_32x32x16_bf16(Xf[kb], wf[kb], a0, 0, 0, 0);
          a1 = __builtin_amdgcn_mfma_f32_32x32x16_bf16(Xf[kb], wf[8 + kb], a1, 0, 0, 0);
          a2 = __builtin_amdgcn_mfma_f32_32x32x16_bf16(Xf[kb], wf[16 + kb], a2, 0, 0, 0);
        }
        const int sl = i & 1;
#pragma unroll
        for (int rg = 0; rg < 16; ++rg) {
          int m = (rg & 3) + 8 * (rg >> 2) + 4 * lh;
          xp[sl][0][j][l31][m] = a0[rg];
          xp[sl][1][j][l31][m] = a1[rg];
          xp[sl][2][j][l31][m] = a2[rg];
        }
      }
    } else {
      if (i >= 1) {
        const int rs = (i - 1) & 1, wsl = i & 1;
        bf16x8 Hf[8];
#pragma unroll
        for (int kb = 0; kb < 8; ++kb)
          Hf[kb] = *(const bf16x8*)(Hbf[rs] + (2 * kb + lh) * 256 + l31 * 8);
        f32x16 a0 = (f32x16)(0.f), a1 = (f32x16)(0.f), a2 = (f32x16)(0.f);
#pragma unroll
        for (int kb = 0; kb < 8; ++kb) {
          a0 = __builtin_amdgcn_mfma_f32_32x32x16_bf16(Hf[kb], wf[kb], a0, 0, 0, 0);
          a1 = __builtin_amdgcn_mfma_f32_32x32x16_bf16(Hf[kb], wf[8 + kb], a1, 0, 0, 0);
          a2 = __builtin_amdgcn_mfma_f32_32x32x16_bf16(Hf[kb], wf[16 + kb], a2, 0, 0, 0);
        }
        const int t = i - 1;
#pragma unroll
        for (int rg = 0; rg < 16; ++rg) {
          int m = (rg & 3) + 8 * (rg >> 2) + 4 * lh;
          float r = fsig(a0[rg] + xp[rs][0][j][l31][m] + bsr);
          float z = fsig(a1[rg] + xp[rs][1][j][l31][m] + bsz);
          float nn_ = ftanh(xp[rs][2][j][l31][m] + bin + r * (a2[rg] + bhn));
          float hnew = (1.f - z) * nn_ + z * h[rg];
          h[rg] = (t < lenr[rg]) ? hnew : h[rg];  // pack_padded mask
          Hbf[wsl][((d >> 3) * 32 + m) * 8 + (d & 7)] = f2bf(h[rg]);
        }
      }
    }
    __syncthreads();
  }

  if (role) {
#pragma unroll
    for (int rg = 0; rg < 16; ++rg) {
      int m = (rg & 3) + 8 * (rg >> 2) + 4 * lh;
      Hout[(size_t)outv[m] * 128 + d] = f2bf(h[rg]);
    }
  }
}

// ---------------------------------------------------------------- GEMM (MFMA, LDS-free)
__global__ __launch_bounds__(256) void k_gemm_mfma(
    const void* __restrict__ A0, const void* __restrict__ A1,
    const void* __restrict__ A2, const u16* __restrict__ A3,
    const u16* __restrict__ A4, int mode, int K,
    const u16* __restrict__ W, const float* __restrict__ bias,
    void* __restrict__ Cout, int out_bf, int M, const int* __restrict__ flag) {
  const int isf = flag[0];
  const int tid = threadIdx.x;
  const int w = tid >> 6, lane = tid & 63;
  const int l31 = lane & 31, lh = lane >> 5;
  const int w01 = w & 1, w23 = w >> 1;
  const int mbase = blockIdx.x * 64 + 32 * w01;
  const int row = mbase + l31;
  const int rowc = row < M ? row : M - 1;

  f32x16 acc0 = (f32x16)(0.f), acc1 = (f32x16)(0.f);
  const int nk = K >> 4;
  for (int kb = 0; kb < nk; ++kb) {
    bf16x8 a;
    if (mode == 0) {
      a = *(const bf16x8*)((const u16*)A0 + (size_t)rowc * K + kb * 16 + lh * 8);
    } else {
      int r5 = 5 * rowc + (kb >> 3);
      int slot = r5 / NN;
      int inner = r5 - slot * NN;
      int koff = (kb & 7) * 16 + lh * 8;
      if (slot < 3) {
        const void* p = (slot == 0) ? A0 : (slot == 1) ? A1 : A2;
        if (isf) {
          const float* fp = (const float*)p + (size_t)inner * 128 + koff;
          float4 v0 = *(const float4*)fp;
          float4 v1 = *(const float4*)(fp + 4);
          a[0] = (short)f2bf(v0.x); a[1] = (short)f2bf(v0.y);
          a[2] = (short)f2bf(v0.z); a[3] = (short)f2bf(v0.w);
          a[4] = (short)f2bf(v1.x); a[5] = (short)f2bf(v1.y);
          a[6] = (short)f2bf(v1.z); a[7] = (short)f2bf(v1.w);
        } else {
          a = *(const bf16x8*)((const u16*)p + (size_t)inner * 128 + koff);
        }
      } else {
        const u16* p = (slot == 3) ? A3 : A4;
        a = *(const bf16x8*)(p + (size_t)inner * 128 + koff);
      }
    }
    const u16* wp = W + (size_t)(64 * w23 + l31) * K + kb * 16 + lh * 8;
    bf16x8 b0 = *(const bf16x8*)wp;
    bf16x8 b1 = *(const bf16x8*)(wp + (size_t)32 * K);
    acc0 = __builtin_amdgcn_mfma_f32_32x32x16_bf16(a, b0, acc0, 0, 0, 0);
    acc1 = __builtin_amdgcn_mfma_f32_32x32x16_bf16(a, b1, acc1, 0, 0, 0);
  }
  const int col0 = 64 * w23 + l31;
  const float bv0 = bias ? bias[col0] : 0.f;
  const float bv1 = bias ? bias[col0 + 32] : 0.f;
#pragma unroll
  for (int rg = 0; rg < 16; ++rg) {
    int m = (rg & 3) + 8 * (rg >> 2) + 4 * lh;
    int grow = mbase + m;
    if (grow < M) {
      float v0 = acc0[rg] + bv0, v1 = acc1[rg] + bv1;
      if (out_bf) {
        ((u16*)Cout)[(size_t)grow * 128 + col0] = f2bf(v0);
        ((u16*)Cout)[(size_t)grow * 128 + col0 + 32] = f2bf(v1);
      } else {
        ((float*)Cout)[(size_t)grow * 128 + col0] = v0;
        ((float*)Cout)[(size_t)grow * 128 + col0 + 32] = v1;
      }
    }
  }
}

// ---------------------------------------------------------------- CSR + degrees
__global__ void k_zero_i(int* __restrict__ p, int n) {
  int i = blockIdx.x * 256 + threadIdx.x;
  if (i < n) p[i] = 0;
}

__global__ void k_hist(const int* __restrict__ dst, int* __restrict__ counts, int E) {
  int e = blockIdx.x * 256 + threadIdx.x;
  if (e < E) atomicAdd(&counts[dst[e]], 1);
}

__global__ void k_scan(const int* __restrict__ counts, int* __restrict__ start,
                       int* __restrict__ cursor, int n) {
  __shared__ int part[256];
  const int C = (n + 255) / 256;
  int tid = threadIdx.x;
  int base = tid * C;
  int s = 0;
  for (int k = 0; k < C; ++k) {
    int i = base + k;
    s += (i < n) ? counts[i] : 0;
  }
  part[tid] = s;
  __syncthreads();
  if (tid == 0) {
    int acc = 0;
    for (int k = 0; k < 256; ++k) { int v = part[k]; part[k] = acc; acc += v; }
  }
  __syncthreads();
  int run = part[tid];
  for (int k = 0; k < C; ++k) {
    int i = base + k;
    if (i < n) {
      int c = counts[i];
      start[i] = run;
      cursor[i] = run;
      run += c;
    }
  }
  if (tid == 255) start[n] = run;
}

__global__ void k_deg_init(float* __restrict__ deg, int n) {
  int i = blockIdx.x * 256 + threadIdx.x;
  if (i < n) deg[i] = 1.f;
}

__global__ void k_deg_acc(const int* __restrict__ dst, const void* __restrict__ w,
                          float* __restrict__ deg, int E, const int* flag) {
  const int isf = flag[0];
  int e = blockIdx.x * 256 + threadIdx.x;
  if (e < E) atomicAdd(&deg[dst[e]], loadf(w, e, isf));
}

__global__ void k_dinv(const float* __restrict__ deg, float* __restrict__ dinv, int n) {
  int i = blockIdx.x * 256 + threadIdx.x;
  if (i < n) dinv[i] = 1.f / sqrtf(deg[i]);
}

// fill CSR with pre-scaled {src, dinv[src]*w} pairs (needs dinv ready)
__global__ void k_fill2(const int* __restrict__ esrc, const int* __restrict__ edst,
                        const void* __restrict__ ew, int* __restrict__ cursor,
                        int2* __restrict__ csr, const float* __restrict__ dinv,
                        int E, const int* flag) {
  const int isf = flag[0];
  int e = blockIdx.x * 256 + threadIdx.x;
  if (e >= E) return;
  int s = esrc[e];
  float c = dinv[s] * loadf(ew, e, isf);
  int p = atomicAdd(&cursor[edst[e]], 1);
  csr[p] = make_int2(s, __float_as_int(c));
}

// ------------------------------------------------- fused GCN gather epilogue
// 1 wave per dst node, lane owns cols (2l, 2l+1); bf16 xw rows (256B/row).
// mode 0: ReLU+LayerNorm -> bf16; mode 1: emb f32 + ReLU bf16.
__global__ __launch_bounds__(256) void k_gcn_gather(
    const int* __restrict__ start, const int2* __restrict__ csr,
    const float* __restrict__ dinv, const u16* __restrict__ xwbf,
    const float* __restrict__ bias, const float* __restrict__ g,
    const float* __restrict__ b, u16* __restrict__ out_bf,
    float* __restrict__ emb_out, int mode) {
  int v = blockIdx.x * 4 + (threadIdx.x >> 6);
  int lane = threadIdx.x & 63;
  if (v >= NN) return;
  const int c0 = 2 * lane;
  float acc0 = 0.f, acc1 = 0.f;
  const int i1 = start[v + 1];
  for (int i = start[v]; i < i1; ++i) {
    int2 e = csr[i];
    float c = __int_as_float(e.y);
    unsigned pv = *(const unsigned*)(xwbf + (size_t)e.x * 128 + c0);
    acc0 += c * bf2f((u16)(pv & 0xffff));
    acc1 += c * bf2f((u16)(pv >> 16));
  }
  float dv = dinv[v];
  unsigned sv = *(const unsigned*)(xwbf + (size_t)v * 128 + c0);
  float y0 = bias[c0] + dv * (dv * bf2f((u16)(sv & 0xffff)) + acc0);
  float y1 = bias[c0 + 1] + dv * (dv * bf2f((u16)(sv >> 16)) + acc1);
  if (mode == 1) {
    *(float2*)(emb_out + (size_t)v * 128 + c0) = make_float2(y0, y1);
    unsigned pk = (unsigned)f2bf(fmaxf(y0, 0.f)) | ((unsigned)f2bf(fmaxf(y1, 0.f)) << 16);
    *(unsigned*)(out_bf + (size_t)v * 128 + c0) = pk;
  } else {
    float x0 = fmaxf(y0, 0.f), x1 = fmaxf(y1, 0.f);
    float s_ = x0 + x1;
#pragma unroll
    for (int off = 32; off; off >>= 1) s_ += __shfl_xor(s_, off);
    float mean = s_ * (1.f / 128.f);
    float e0 = x0 - mean, e1 = x1 - mean;
    float vv = e0 * e0 + e1 * e1;
#pragma unroll
    for (int off = 32; off; off >>= 1) vv += __shfl_xor(vv, off);
    float inv = 1.f / sqrtf(vv * (1.f / 128.f) + 1e-5f);
    unsigned pk = (unsigned)f2bf(e0 * inv * g[c0] + b[c0]) |
                  ((unsigned)f2bf(e1 * inv * g[c0 + 1] + b[c0 + 1]) << 16);
    *(unsigned*)(out_bf + (size_t)v * 128 + c0) = pk;
  }
}

// ---------------------------------------------------------------- head
__global__ __launch_bounds__(256) void k_mp2_ls(
    const float* __restrict__ t1, const float* __restrict__ W,
    const float* __restrict__ b2, float* __restrict__ outp, int nrows) {
  int wid = (blockIdx.x * 256 + threadIdx.x) >> 6;
  int lane = threadIdx.x & 63;
  if (wid >= nrows) return;
  const float* row = t1 + (size_t)wid * DD;
  float x0 = row[lane], x1 = row[lane + 64];
  float p0 = x0 * W[lane] + x1 * W[lane + 64];
  float p1 = x0 * W[DD + lane] + x1 * W[DD + 64 + lane];
#pragma unroll
  for (int off = 32; off; off >>= 1) {
    p0 += __shfl_xor(p0, off);
    p1 += __shfl_xor(p1, off);
  }
  if (lane == 0) {
    float v0 = p0 + b2[0], v1 = p1 + b2[1];
    float m = fmaxf(v0, v1);
    float ls = m + logf(__expf(v0 - m) + __expf(v1 - m));
    outp[(size_t)wid * 2 + 0] = v0 - ls;
    outp[(size_t)wid * 2 + 1] = v1 - ls;
  }
}

__global__ void k_out(const float* __restrict__ stage, void* __restrict__ dout,
                      int n, const int* flag) {
  const int isf = flag[0];
  int i = blockIdx.x * 256 + threadIdx.x;
  if (i >= n) return;
  if (isf) ((float*)dout)[i] = stage[i];
  else ((u16*)dout)[i] = f2bf(stage[i]);
}

// ---------------------------------------------------------------- launch
extern "C" void kernel_launch(void* const* d_in, const int* in_sizes, int n_in,
                              void* d_out, int out_size, void* d_ws, size_t ws_size,
                              hipStream_t stream) {
  const int* idx_lp = (const int*)d_in[0];
  const int* len_lp = (const int*)d_in[1];
  const int* idx_ns = (const int*)d_in[2];
  const int* len_ns = (const int*)d_in[3];
  const void* x_ref = d_in[4];
  const void* x_def = d_in[5];
  const void* x_pdt = d_in[6];
  const int* eidx   = (const int*)d_in[7];
  const void* ew    = d_in[8];
  const void* lp_emb = d_in[9];

  // ---- workspace layout (sequential allocator, ~68 MB) ----
  char* cur = (char*)d_ws;
  auto alloc = [&](size_t bytes, size_t align) -> void* {
    size_t a = ((size_t)cur + align - 1) & ~(align - 1);
    cur = (char*)(a + bytes);
    return (void*)a;
  };
  int* flag     = (int*)alloc(64, 64);
  float* smallW = (float*)alloc(3104 * 4, 16);
  float* f_xw   = (float*)alloc((size_t)NN * DD * 4, 16);
  float* f_deg  = (float*)alloc(NN * 4, 16);
  float* f_dinv = (float*)alloc(NN * 4, 16);
  float* stage  = (float*)alloc(((size_t)NN * DD + 2 * NN) * 4, 16);
  int* counts   = (int*)alloc(NN * 4, 16);
  int* startA   = (int*)alloc((NN + 1) * 4, 16);
  int* cursorE  = (int*)alloc(NN * 4, 16);
  int* bins     = (int*)alloc(128 * 4, 16);  // [0:32) lp hist, [32:64) lp cur,
                                             // [64:96) ns hist, [96:128) ns cur
  int* perm_lp  = (int*)alloc(PP * NN * 4, 16);
  int* perm_ns  = (int*)alloc(NN * 4, 16);
  int2* csr2    = (int2*)alloc((size_t)EE * 8, 16);
  u16* ub       = (u16*)alloc((size_t)20233216 * 2, 16);
  u16* embbf_lp = ub;
  u16* embbf_ns = ub + 640000;
  u16* wg_lpih  = ub + 1920000;
  u16* wg_lphh  = ub + 1969152;
  u16* wg_nsih  = ub + 2018304;
  u16* wg_nshh  = ub + 2067456;
  u16* wg_lpfc  = ub + 2116608;
  u16* wg_allfc = ub + 2165760;
  u16* wg_c1    = ub + 2247680;
  u16* wg_c2    = ub + 2264064;
  u16* wg_c3    = ub + 2280448;
  u16* wg_mp1   = ub + 2296832;
  u16* hbf_lp   = ub + 2313216;   // [3N,128]
  u16* hbf_ns   = ub + 9993216;   // [N,128]
  u16* lp_bf    = ub + 12553216;  // [N,128]
  u16* xcur_bf  = ub + 15113216;  // [N,128]
  u16* xw_bf    = ub + 17673216;  // [N,128]
  u16* relu_bf  = hbf_lp;         // dead after lp_fc

  static const int fn[16] = {384, 384, 384, 384, 128, 128, 128, 128,
                             128, 128, 128, 128, 128, 128, 256, 2};
  static const int fsrc[16] = {13, 14, 17, 18, 20, 22, 24, 26,
                               28, 29, 30, 31, 32, 34, 35, 36};
  CvtJobs jf;
  int foff[16];
  {
    int off = 0;
    for (int j = 0; j < 16; ++j) {
      jf.src[j] = d_in[fsrc[j]];
      jf.off[j] = off;
      jf.n[j] = fn[j];
      foff[j] = off;
      off += fn[j];
    }
  }
  float* b_lpbih = smallW + foff[0];
  float* b_lpbhh = smallW + foff[1];
  float* b_nsbih = smallW + foff[2];
  float* b_nsbhh = smallW + foff[3];
  float* b_lpfc  = smallW + foff[4];
  float* b_allfc = smallW + foff[5];
  float* b_conv[3] = {smallW + foff[6], smallW + foff[7], smallW + foff[8]};
  float* g_ln[2] = {smallW + foff[9], smallW + foff[11]};
  float* b_ln[2] = {smallW + foff[10], smallW + foff[12]};
  float* b_mp1   = smallW + foff[13];
  float* w_mp2   = smallW + foff[14];
  float* b_mp2   = smallW + foff[15];

  static const int bn[12] = {640000, 1280000, 49152, 49152, 49152, 49152,
                             49152, 81920, 16384, 16384, 16384, 16384};
  static const int bsrc[12] = {9, 10, 11, 12, 15, 16, 19, 21, 23, 25, 27, 33};
  static const int boff[12] = {0, 640000, 1920000, 1969152, 2018304, 2067456,
                               2116608, 2165760, 2247680, 2264064, 2280448,
                               2296832};
  CvtJobsB jb;
  for (int j = 0; j < 12; ++j) {
    jb.src[j] = d_in[bsrc[j]];
    jb.off[j] = boff[j];
    jb.n[j] = bn[j];
  }

  const int* e_src = eidx;
  const int* e_dst = eidx + EE;

  // 0. dtype detection
  k_detect<<<1, 256, 0, stream>>>(lp_emb, flag);

  // 1. conversions
  k_cvt_batch<<<16, 256, 0, stream>>>(jf, smallW, flag);
  k_cvtb<<<12 * 64, 256, 0, stream>>>(jb, ub, flag);

  // 2. length sorts (LP and NS)
  k_zero_i<<<1, 256, 0, stream>>>(bins, 128);
  k_lenhist<<<(PP * NN + 255) / 256, 256, 0, stream>>>(len_lp, bins, PP * NN, 0);
  k_lenhist<<<(NN + 255) / 256, 256, 0, stream>>>(len_ns, bins + 64, NN, 1);
  k_binscan<<<1, 64, 0, stream>>>(bins, bins + 32, 32);
  k_binscan<<<1, 64, 0, stream>>>(bins + 64, bins + 96, 32);
  k_lenfill<<<(PP * NN + 255) / 256, 256, 0, stream>>>(len_lp, bins + 32, perm_lp,
                                                       PP * NN, 0);
  k_lenfill<<<(NN + 255) / 256, 256, 0, stream>>>(len_ns, bins + 96, perm_ns, NN, 1);

  // 3. degrees + CSR (pre-scaled edge coefficients)
  k_zero_i<<<(NN + 255) / 256, 256, 0, stream>>>(counts, NN);
  k_hist<<<(EE + 255) / 256, 256, 0, stream>>>(e_dst, counts, EE);
  k_scan<<<1, 256, 0, stream>>>(counts, startA, cursorE, NN);
  k_deg_init<<<(NN + 255) / 256, 256, 0, stream>>>(f_deg, NN);
  k_deg_acc<<<(EE + 255) / 256, 256, 0, stream>>>(e_dst, ew, f_deg, EE, flag);
  k_dinv<<<(NN + 255) / 256, 256, 0, stream>>>(f_deg, f_dinv, NN);
  k_fill2<<<(EE + 255) / 256, 256, 0, stream>>>(e_src, e_dst, ew, cursorE, csr2,
                                                f_dinv, EE, flag);

  // 4. merged, length-sorted GRUs (one dispatch: 1875 LP + 625 NS blocks)
  const int nbLP = PP * NN / 32, nbNS = NN / 32;
  k_gru4<<<nbLP + nbNS, 512, 0, stream>>>(
      perm_lp, perm_ns, nbLP, embbf_lp, embbf_ns, idx_lp, idx_ns, len_lp, len_ns,
      wg_lpih, wg_lphh, wg_nsih, wg_nshh, b_lpbih, b_lpbhh, b_nsbih, b_nsbhh,
      hbf_lp, hbf_ns);

  const int gg = (NN + 63) / 64;
  // 5. lp_fc: hbf_lp flat [3N,128] viewed [N,384] == faithful reshape
  k_gemm_mfma<<<gg, 256, 0, stream>>>(hbf_lp, nullptr, nullptr, nullptr, nullptr,
                                      0, 384, wg_lpfc, b_lpfc, lp_bf, 1, NN, flag);
  // 6. all_fc: scramble-gather {pdt, ref, def, lp, ns} -> xcur_bf
  k_gemm_mfma<<<gg, 256, 0, stream>>>(x_pdt, x_ref, x_def, lp_bf, hbf_ns,
                                      1, 640, wg_allfc, b_allfc, xcur_bf, 1, NN, flag);

  // 7. three GCN layers: bf16 GEMM out + fused CSR gather epilogue
  const u16* wgc[3] = {wg_c1, wg_c2, wg_c3};
  for (int l = 0; l < 3; ++l) {
    k_gemm_mfma<<<gg, 256, 0, stream>>>(xcur_bf, nullptr, nullptr, nullptr, nullptr,
                                        0, DD, wgc[l], nullptr, xw_bf, 1, NN, flag);
    if (l < 2) {
      k_gcn_gather<<<NN / 4, 256, 0, stream>>>(startA, csr2, f_dinv, xw_bf,
                                               b_conv[l], g_ln[l], b_ln[l],
                                               xcur_bf, nullptr, 0);
    } else {
      k_gcn_gather<<<NN / 4, 256, 0, stream>>>(startA, csr2, f_dinv, xw_bf,
                                               b_conv[l], nullptr, nullptr,
                                               relu_bf, stage, 1);
    }
  }

  // 8. mp head (no activation between mp1/mp2) + log_softmax
  k_gemm_mfma<<<gg, 256, 0, stream>>>(relu_bf, nullptr, nullptr, nullptr, nullptr,
                                      0, DD, wg_mp1, b_mp1, f_xw, 0, NN, flag);
  k_mp2_ls<<<(NN + 3) / 4, 256, 0, stream>>>(f_xw, w_mp2, b_mp2,
                                             stage + (size_t)NN * DD, NN);

  // 9. store in detected output dtype
  k_out<<<(out_size + 255) / 256, 256, 0, stream>>>(stage, d_out, out_size, flag);
}

// Round 8
// 1232.260 us; speedup vs baseline: 1.2056x; 1.2056x over previous
//
#include <hip/hip_runtime.h>
#include <math.h>

typedef unsigned short u16;
typedef short bf16x4 __attribute__((ext_vector_type(4)));
typedef short bf16x8 __attribute__((ext_vector_type(8)));
typedef float f32x16 __attribute__((ext_vector_type(16)));

#define NN 20000
#define PP 3
#define TLP 10
#define TNS 20
#define DD 128
#define EE 640000

__device__ __forceinline__ float bf2f(u16 u) {
  union { unsigned u; float f; } v; v.u = ((unsigned)u) << 16; return v.f;
}
__device__ __forceinline__ u16 f2bf(float f) {
  union { float f; unsigned u; } v; v.f = f;
  unsigned r = v.u + 0x7fffu + ((v.u >> 16) & 1u);
  return (u16)(r >> 16);
}
__device__ __forceinline__ float fsig(float x) {
  return __fdividef(1.f, 1.f + __expf(-x));
}
__device__ __forceinline__ float ftanh(float x) {
  return fmaf(2.f, __fdividef(1.f, 1.f + __expf(-2.f * x)), -1.f);
}
__device__ __forceinline__ float loadf(const void* p, size_t i, int isf) {
  return isf ? ((const float*)p)[i] : bf2f(((const u16*)p)[i]);
}

// ------------------------------------------------------------- dtype detect
__global__ void k_detect(const void* probe, int* flag) {
  __shared__ int any;
  if (threadIdx.x == 0) any = 0;
  __syncthreads();
  const u16* p = (const u16*)probe;
  int bad = 0;
  for (int i = threadIdx.x; i < 4096; i += 256) {
    int e = (p[2 * i] >> 7) & 0xFF;
    if (e >= 0x9F) bad = 1;
  }
  if (bad) atomicOr(&any, 1);
  __syncthreads();
  if (threadIdx.x == 0) flag[0] = any;  // 1 = f32, 0 = bf16
}

// ------------------------------------------------------------- converters
struct CvtJobs {
  const void* src[16];
  int off[16];
  int n[16];
};

__global__ void k_cvt_batch(CvtJobs jobs, float* dst, const int* flag) {
  const int isf = flag[0];
  const void* s = jobs.src[blockIdx.x];
  float* d = dst + jobs.off[blockIdx.x];
  const int n = jobs.n[blockIdx.x];
  for (int i = threadIdx.x; i < n; i += 256) d[i] = loadf(s, i, isf);
}

struct CvtJobsB {
  const void* src[12];
  int off[12];
  int n[12];
};

__global__ void k_cvtb(CvtJobsB j, u16* __restrict__ dst, const int* flag) {
  const int isf = flag[0];
  const int job = blockIdx.x >> 6;
  const int chunk = blockIdx.x & 63;
  const void* s = j.src[job];
  u16* d = dst + j.off[job];
  const int n = j.n[job];
  for (int i = chunk * 256 + threadIdx.x; i < n; i += 64 * 256)
    d[i] = f2bf(loadf(s, i, isf));
}

// ------------------------------------------------------------- length sort
// ballot-aggregated counting sort: one atomic per wave per bin.
__global__ void k_lenhist2(const int* __restrict__ lens, int* __restrict__ bins,
                           int numSeq, int mode, int nb) {
  int sg = blockIdx.x * 256 + threadIdx.x;
  int lane = threadIdx.x & 63;
  int bin = 0;
  if (sg < numSeq) {
    int row = (mode == 0) ? ((sg % NN) * PP + sg / NN) : sg;
    bin = lens[row];
  }
  for (int b = 1; b <= nb; ++b) {
    unsigned long long m = __ballot(bin == b);
    if (m) {
      int leader = (int)(__ffsll((long long)m) - 1);
      if (lane == leader) atomicAdd(&bins[b], (int)__popcll(m));
    }
  }
}

__global__ void k_binscan(const int* __restrict__ bins, int* __restrict__ cursor,
                          int nb) {
  if (threadIdx.x == 0) {
    int acc = 0;
    for (int k = 0; k < nb; ++k) { cursor[k] = acc; acc += bins[k]; }
  }
}

__global__ void k_lenfill2(const int* __restrict__ lens, int* __restrict__ cursor,
                           int* __restrict__ perm, int numSeq, int mode, int nb) {
  int sg = blockIdx.x * 256 + threadIdx.x;
  int lane = threadIdx.x & 63;
  int bin = 0;
  if (sg < numSeq) {
    int row = (mode == 0) ? ((sg % NN) * PP + sg / NN) : sg;
    bin = lens[row];
  }
  for (int b = 1; b <= nb; ++b) {
    unsigned long long m = __ballot(bin == b);
    if (m) {
      int leader = (int)(__ffsll((long long)m) - 1);
      int base = 0;
      if (lane == leader) base = atomicAdd(&cursor[b], (int)__popcll(m));
      base = __shfl(base, leader);
      if (bin == b) {
        int rank = (int)__popcll(m & ((1ull << lane) - 1ull));
        perm[base + rank] = sg;
      }
    }
  }
}

// ---------------------------------------------------------------- GRU v5
// 512 thr = 8 waves, 32 seqs/block, length-sorted, longest blocks first.
// Waves 0-3: X producers (Wih frags) -> bf16 xp ring (packed b64).
// Waves 4-7: H consumers (Whh frags); h f32 in C-layout regs.
// Hbf2 [m][132] layout: b16 writes 2-way-free, b64 reads conflict-free.
__global__ __launch_bounds__(512, 2) void k_gru5(
    const int* __restrict__ permLP, const int* __restrict__ permNS, int nbNS,
    const u16* __restrict__ embLP, const u16* __restrict__ embNS,
    const int* __restrict__ idxLP, const int* __restrict__ idxNS,
    const int* __restrict__ lenLP, const int* __restrict__ lenNS,
    const u16* __restrict__ WihLP, const u16* __restrict__ WhhLP,
    const u16* __restrict__ WihNS, const u16* __restrict__ WhhNS,
    const float* __restrict__ bihLP, const float* __restrict__ bhhLP,
    const float* __restrict__ bihNS, const float* __restrict__ bhhNS,
    u16* __restrict__ HoutLP, u16* __restrict__ HoutNS, int nbLP) {
  __shared__ u16 xp[2][3][128][36];   // [slot][gate][d][m] bf16, b64-packed
  __shared__ u16 Hbf2[2][32][132];    // [slot][m][d], pad 132
  __shared__ int ivs[TNS][32];
  __shared__ int rowv[32], outv[32], lenv_s[32];
  __shared__ int Tbs;

  const int bid = blockIdx.x;
  const int isNS = bid < nbNS;
  // longest-first: NS family first, descending within each family
  const int chunk = isNS ? (nbNS - 1 - bid) : (nbLP - 1 - (bid - nbNS));
  const int* perm = isNS ? (permNS + chunk * 32) : (permLP + chunk * 32);
  const u16* embbf = isNS ? embNS : embLP;
  const int* idx = isNS ? idxNS : idxLP;
  const int* lens = isNS ? lenNS : lenLP;
  const u16* Wih = isNS ? WihNS : WihLP;
  const u16* Whh = isNS ? WhhNS : WhhLP;
  const float* bih = isNS ? bihNS : bihLP;
  const float* bhh = isNS ? bhhNS : bhhLP;
  u16* Hout = isNS ? HoutNS : HoutLP;
  const int T = isNS ? TNS : TLP;

  const int tid = threadIdx.x;
  const int w = tid >> 6, lane = tid & 63;
  const int l31 = lane & 31, lh = lane >> 5;
  const int role = w >> 2;  // 0 = X producer, 1 = H consumer
  const int j = w & 3;
  const int d = 32 * j + l31;

  if (tid < 32) {
    int sg = perm[tid];
    int row = isNS ? sg : ((sg % NN) * PP + sg / NN);
    rowv[tid] = row;
    outv[tid] = sg;
    lenv_s[tid] = lens[row];
  }
  __syncthreads();
  if (tid == 0) {
    int m = 1;
    for (int k = 0; k < 32; ++k) m = max(m, lenv_s[k]);
    Tbs = m;
  }
  __syncthreads();
  const int Tb = Tbs;

  for (int z = tid; z < Tb * 32; z += 512) {
    int s = z & 31, t = z >> 5;
    ivs[t][s] = idx[(size_t)rowv[s] * T + t];
  }
  // zero Hbf2 slot 0 (32*132 u16 = 4224 elems = 2112 u32)
  for (int z = tid; z < 2112; z += 512) ((unsigned*)Hbf2[0])[z] = 0u;

  bf16x8 wf[24];
  {
    const u16* Ws = role ? Whh : Wih;
#pragma unroll
    for (int g = 0; g < 3; ++g)
#pragma unroll
      for (int kb = 0; kb < 8; ++kb)
        wf[g * 8 + kb] =
            *(const bf16x8*)(Ws + (size_t)(128 * g + d) * 128 + kb * 16 + lh * 8);
  }
  const float bsr = bih[d] + bhh[d];
  const float bsz = bih[128 + d] + bhh[128 + d];
  const float bin = bih[256 + d];
  const float bhn = bhh[256 + d];

  __syncthreads();
  int lenr[16];
#pragma unroll
  for (int rg = 0; rg < 16; ++rg)
    lenr[rg] = lenv_s[(rg & 3) + 8 * (rg >> 2) + 4 * lh];

  float h[16];
#pragma unroll
  for (int rg = 0; rg < 16; ++rg) h[rg] = 0.f;

  for (int i = 0; i <= Tb; ++i) {
    if (!role) {
      if (i < Tb) {
        bf16x8 Xf[8];
        const u16* erow = embbf + (size_t)ivs[i][l31] * 128 + lh * 8;
#pragma unroll
        for (int kb = 0; kb < 8; ++kb) Xf[kb] = *(const bf16x8*)(erow + kb * 16);
        f32x16 a0 = (f32x16)(0.f), a1 = (f32x16)(0.f), a2 = (f32x16)(0.f);
#pragma unroll
        for (int kb = 0; kb < 8; ++kb) {
          a0 = __builtin_amdgcn_mfma_f32_32x32x16_bf16(Xf[kb], wf[kb], a0, 0, 0, 0);
          a1 = __builtin_amdgcn_mfma_f32_32x32x16_bf16(Xf[kb], wf[8 + kb], a1, 0, 0, 0);
          a2 = __builtin_amdgcn_mfma_f32_32x32x16_bf16(Xf[kb], wf[16 + kb], a2, 0, 0, 0);
        }
        const int sl = i & 1;
        // packed b64 writes: quad rq -> m base 8rq+4lh (4 consecutive m)
#pragma unroll
        for (int rq = 0; rq < 4; ++rq) {
          int mo = 8 * rq + 4 * lh;
          bf16x4 p0, p1, p2;
#pragma unroll
          for (int q = 0; q < 4; ++q) {
            p0[q] = (short)f2bf(a0[4 * rq + q]);
            p1[q] = (short)f2bf(a1[4 * rq + q]);
            p2[q] = (short)f2bf(a2[4 * rq + q]);
          }
          *(bf16x4*)(&xp[sl][0][d][mo]) = p0;
          *(bf16x4*)(&xp[sl][1][d][mo]) = p1;
          *(bf16x4*)(&xp[sl][2][d][mo]) = p2;
        }
      }
    } else {
      if (i >= 1) {
        const int rs = (i - 1) & 1, wsl = i & 1;
        bf16x8 Hf[8];
#pragma unroll
        for (int kb = 0; kb < 8; ++kb) {
          bf16x4 lo = *(const bf16x4*)(&Hbf2[rs][l31][16 * kb + 8 * lh]);
          bf16x4 hi = *(const bf16x4*)(&Hbf2[rs][l31][16 * kb + 8 * lh + 4]);
          Hf[kb] = __builtin_shufflevector(lo, hi, 0, 1, 2, 3, 4, 5, 6, 7);
        }
        f32x16 a0 = (f32x16)(0.f), a1 = (f32x16)(0.f), a2 = (f32x16)(0.f);
#pragma unroll
        for (int kb = 0; kb < 8; ++kb) {
          a0 = __builtin_amdgcn_mfma_f32_32x32x16_bf16(Hf[kb], wf[kb], a0, 0, 0, 0);
          a1 = __builtin_amdgcn_mfma_f32_32x32x16_bf16(Hf[kb], wf[8 + kb], a1, 0, 0, 0);
          a2 = __builtin_amdgcn_mfma_f32_32x32x16_bf16(Hf[kb], wf[16 + kb], a2, 0, 0, 0);
        }
        const int t = i - 1;
#pragma unroll
        for (int rq = 0; rq < 4; ++rq) {
          int mo = 8 * rq + 4 * lh;
          bf16x4 x0 = *(const bf16x4*)(&xp[rs][0][d][mo]);
          bf16x4 x1 = *(const bf16x4*)(&xp[rs][1][d][mo]);
          bf16x4 x2 = *(const bf16x4*)(&xp[rs][2][d][mo]);
#pragma unroll
          for (int q = 0; q < 4; ++q) {
            int rg = 4 * rq + q;
            float r = fsig(a0[rg] + bf2f((u16)x0[q]) + bsr);
            float z = fsig(a1[rg] + bf2f((u16)x1[q]) + bsz);
            float nn_ = ftanh(bf2f((u16)x2[q]) + bin + r * (a2[rg] + bhn));
            float hnew = (1.f - z) * nn_ + z * h[rg];
            h[rg] = (t < lenr[rg]) ? hnew : h[rg];  // pack_padded mask
            Hbf2[wsl][mo + q][d] = f2bf(h[rg]);
          }
        }
      }
    }
    __syncthreads();
  }

  if (role) {
#pragma unroll
    for (int rg = 0; rg < 16; ++rg) {
      int m = (rg & 3) + 8 * (rg >> 2) + 4 * lh;
      Hout[(size_t)outv[m] * 128 + d] = f2bf(h[rg]);
    }
  }
}

// ---------------------------------------------------------------- GEMM (MFMA, LDS-free)
__global__ __launch_bounds__(256) void k_gemm_mfma(
    const void* __restrict__ A0, const void* __restrict__ A1,
    const void* __restrict__ A2, const u16* __restrict__ A3,
    const u16* __restrict__ A4, int mode, int K,
    const u16* __restrict__ W, const float* __restrict__ bias,
    void* __restrict__ Cout, int out_bf, int M, const int* __restrict__ flag) {
  const int isf = flag[0];
  const int tid = threadIdx.x;
  const int w = tid >> 6, lane = tid & 63;
  const int l31 = lane & 31, lh = lane >> 5;
  const int w01 = w & 1, w23 = w >> 1;
  const int mbase = blockIdx.x * 64 + 32 * w01;
  const int row = mbase + l31;
  const int rowc = row < M ? row : M - 1;

  f32x16 acc0 = (f32x16)(0.f), acc1 = (f32x16)(0.f);
  const int nk = K >> 4;
  for (int kb = 0; kb < nk; ++kb) {
    bf16x8 a;
    if (mode == 0) {
      a = *(const bf16x8*)((const u16*)A0 + (size_t)rowc * K + kb * 16 + lh * 8);
    } else {
      int r5 = 5 * rowc + (kb >> 3);
      int slot = r5 / NN;
      int inner = r5 - slot * NN;
      int koff = (kb & 7) * 16 + lh * 8;
      if (slot < 3) {
        const void* p = (slot == 0) ? A0 : (slot == 1) ? A1 : A2;
        if (isf) {
          const float* fp = (const float*)p + (size_t)inner * 128 + koff;
          float4 v0 = *(const float4*)fp;
          float4 v1 = *(const float4*)(fp + 4);
          a[0] = (short)f2bf(v0.x); a[1] = (short)f2bf(v0.y);
          a[2] = (short)f2bf(v0.z); a[3] = (short)f2bf(v0.w);
          a[4] = (short)f2bf(v1.x); a[5] = (short)f2bf(v1.y);
          a[6] = (short)f2bf(v1.z); a[7] = (short)f2bf(v1.w);
        } else {
          a = *(const bf16x8*)((const u16*)p + (size_t)inner * 128 + koff);
        }
      } else {
        const u16* p = (slot == 3) ? A3 : A4;
        a = *(const bf16x8*)(p + (size_t)inner * 128 + koff);
      }
    }
    const u16* wp = W + (size_t)(64 * w23 + l31) * K + kb * 16 + lh * 8;
    bf16x8 b0 = *(const bf16x8*)wp;
    bf16x8 b1 = *(const bf16x8*)(wp + (size_t)32 * K);
    acc0 = __builtin_amdgcn_mfma_f32_32x32x16_bf16(a, b0, acc0, 0, 0, 0);
    acc1 = __builtin_amdgcn_mfma_f32_32x32x16_bf16(a, b1, acc1, 0, 0, 0);
  }
  const int col0 = 64 * w23 + l31;
  const float bv0 = bias ? bias[col0] : 0.f;
  const float bv1 = bias ? bias[col0 + 32] : 0.f;
#pragma unroll
  for (int rg = 0; rg < 16; ++rg) {
    int m = (rg & 3) + 8 * (rg >> 2) + 4 * lh;
    int grow = mbase + m;
    if (grow < M) {
      float v0 = acc0[rg] + bv0, v1 = acc1[rg] + bv1;
      if (out_bf) {
        ((u16*)Cout)[(size_t)grow * 128 + col0] = f2bf(v0);
        ((u16*)Cout)[(size_t)grow * 128 + col0 + 32] = f2bf(v1);
      } else {
        ((float*)Cout)[(size_t)grow * 128 + col0] = v0;
        ((float*)Cout)[(size_t)grow * 128 + col0 + 32] = v1;
      }
    }
  }
}

// ---------------------------------------------------------------- CSR + degrees
__global__ void k_zero_i(int* __restrict__ p, int n) {
  int i = blockIdx.x * 256 + threadIdx.x;
  if (i < n) p[i] = 0;
}

__global__ void k_hist(const int* __restrict__ dst, int* __restrict__ counts, int E) {
  int e = blockIdx.x * 256 + threadIdx.x;
  if (e < E) atomicAdd(&counts[dst[e]], 1);
}

__global__ void k_scan(const int* __restrict__ counts, int* __restrict__ start,
                       int* __restrict__ cursor, int n) {
  __shared__ int part[256];
  const int C = (n + 255) / 256;
  int tid = threadIdx.x;
  int base = tid * C;
  int s = 0;
  for (int k = 0; k < C; ++k) {
    int i = base + k;
    s += (i < n) ? counts[i] : 0;
  }
  part[tid] = s;
  __syncthreads();
  if (tid == 0) {
    int acc = 0;
    for (int k = 0; k < 256; ++k) { int v = part[k]; part[k] = acc; acc += v; }
  }
  __syncthreads();
  int run = part[tid];
  for (int k = 0; k < C; ++k) {
    int i = base + k;
    if (i < n) {
      int c = counts[i];
      start[i] = run;
      cursor[i] = run;
      run += c;
    }
  }
  if (tid == 255) start[n] = run;
}

__global__ void k_deg_init(float* __restrict__ deg, int n) {
  int i = blockIdx.x * 256 + threadIdx.x;
  if (i < n) deg[i] = 1.f;
}

__global__ void k_deg_acc(const int* __restrict__ dst, const void* __restrict__ w,
                          float* __restrict__ deg, int E, const int* flag) {
  const int isf = flag[0];
  int e = blockIdx.x * 256 + threadIdx.x;
  if (e < E) atomicAdd(&deg[dst[e]], loadf(w, e, isf));
}

__global__ void k_dinv(const float* __restrict__ deg, float* __restrict__ dinv, int n) {
  int i = blockIdx.x * 256 + threadIdx.x;
  if (i < n) dinv[i] = 1.f / sqrtf(deg[i]);
}

__global__ void k_fill2(const int* __restrict__ esrc, const int* __restrict__ edst,
                        const void* __restrict__ ew, int* __restrict__ cursor,
                        int2* __restrict__ csr, const float* __restrict__ dinv,
                        int E, const int* flag) {
  const int isf = flag[0];
  int e = blockIdx.x * 256 + threadIdx.x;
  if (e >= E) return;
  int s = esrc[e];
  float c = dinv[s] * loadf(ew, e, isf);
  int p = atomicAdd(&cursor[edst[e]], 1);
  csr[p] = make_int2(s, __float_as_int(c));
}

// ------------------------------------------------- fused GCN gather epilogue
__global__ __launch_bounds__(256) void k_gcn_gather(
    const int* __restrict__ start, const int2* __restrict__ csr,
    const float* __restrict__ dinv, const u16* __restrict__ xwbf,
    const float* __restrict__ bias, const float* __restrict__ g,
    const float* __restrict__ b, u16* __restrict__ out_bf,
    float* __restrict__ emb_out, int mode) {
  int v = blockIdx.x * 4 + (threadIdx.x >> 6);
  int lane = threadIdx.x & 63;
  if (v >= NN) return;
  const int c0 = 2 * lane;
  float acc0 = 0.f, acc1 = 0.f;
  int i = start[v];
  const int i1 = start[v + 1];
  // 2x manual unroll for memory-level parallelism
  for (; i + 2 <= i1; i += 2) {
    int2 e0 = csr[i], e1 = csr[i + 1];
    unsigned p0 = *(const unsigned*)(xwbf + (size_t)e0.x * 128 + c0);
    unsigned p1 = *(const unsigned*)(xwbf + (size_t)e1.x * 128 + c0);
    float cc0 = __int_as_float(e0.y), cc1 = __int_as_float(e1.y);
    acc0 += cc0 * bf2f((u16)(p0 & 0xffff)) + cc1 * bf2f((u16)(p1 & 0xffff));
    acc1 += cc0 * bf2f((u16)(p0 >> 16)) + cc1 * bf2f((u16)(p1 >> 16));
  }
  if (i < i1) {
    int2 e = csr[i];
    float c = __int_as_float(e.y);
    unsigned pv = *(const unsigned*)(xwbf + (size_t)e.x * 128 + c0);
    acc0 += c * bf2f((u16)(pv & 0xffff));
    acc1 += c * bf2f((u16)(pv >> 16));
  }
  float dv = dinv[v];
  unsigned sv = *(const unsigned*)(xwbf + (size_t)v * 128 + c0);
  float y0 = bias[c0] + dv * (dv * bf2f((u16)(sv & 0xffff)) + acc0);
  float y1 = bias[c0 + 1] + dv * (dv * bf2f((u16)(sv >> 16)) + acc1);
  if (mode == 1) {
    *(float2*)(emb_out + (size_t)v * 128 + c0) = make_float2(y0, y1);
    unsigned pk = (unsigned)f2bf(fmaxf(y0, 0.f)) | ((unsigned)f2bf(fmaxf(y1, 0.f)) << 16);
    *(unsigned*)(out_bf + (size_t)v * 128 + c0) = pk;
  } else {
    float x0 = fmaxf(y0, 0.f), x1 = fmaxf(y1, 0.f);
    float s_ = x0 + x1;
#pragma unroll
    for (int off = 32; off; off >>= 1) s_ += __shfl_xor(s_, off);
    float mean = s_ * (1.f / 128.f);
    float e0 = x0 - mean, e1 = x1 - mean;
    float vv = e0 * e0 + e1 * e1;
#pragma unroll
    for (int off = 32; off; off >>= 1) vv += __shfl_xor(vv, off);
    float inv = 1.f / sqrtf(vv * (1.f / 128.f) + 1e-5f);
    unsigned pk = (unsigned)f2bf(e0 * inv * g[c0] + b[c0]) |
                  ((unsigned)f2bf(e1 * inv * g[c0 + 1] + b[c0 + 1]) << 16);
    *(unsigned*)(out_bf + (size_t)v * 128 + c0) = pk;
  }
}

// ---------------------------------------------------------------- head
__global__ __launch_bounds__(256) void k_mp2_ls(
    const float* __restrict__ t1, const float* __restrict__ W,
    const float* __restrict__ b2, float* __restrict__ outp, int nrows) {
  int wid = (blockIdx.x * 256 + threadIdx.x) >> 6;
  int lane = threadIdx.x & 63;
  if (wid >= nrows) return;
  const float* row = t1 + (size_t)wid * DD;
  float x0 = row[lane], x1 = row[lane + 64];
  float p0 = x0 * W[lane] + x1 * W[lane + 64];
  float p1 = x0 * W[DD + lane] + x1 * W[DD + 64 + lane];
#pragma unroll
  for (int off = 32; off; off >>= 1) {
    p0 += __shfl_xor(p0, off);
    p1 += __shfl_xor(p1, off);
  }
  if (lane == 0) {
    float v0 = p0 + b2[0], v1 = p1 + b2[1];
    float m = fmaxf(v0, v1);
    float ls = m + logf(__expf(v0 - m) + __expf(v1 - m));
    outp[(size_t)wid * 2 + 0] = v0 - ls;
    outp[(size_t)wid * 2 + 1] = v1 - ls;
  }
}

__global__ void k_out(const float* __restrict__ stage, void* __restrict__ dout,
                      int n, const int* flag) {
  const int isf = flag[0];
  int i = blockIdx.x * 256 + threadIdx.x;
  if (i >= n) return;
  if (isf) ((float*)dout)[i] = stage[i];
  else ((u16*)dout)[i] = f2bf(stage[i]);
}

// ---------------------------------------------------------------- launch
extern "C" void kernel_launch(void* const* d_in, const int* in_sizes, int n_in,
                              void* d_out, int out_size, void* d_ws, size_t ws_size,
                              hipStream_t stream) {
  const int* idx_lp = (const int*)d_in[0];
  const int* len_lp = (const int*)d_in[1];
  const int* idx_ns = (const int*)d_in[2];
  const int* len_ns = (const int*)d_in[3];
  const void* x_ref = d_in[4];
  const void* x_def = d_in[5];
  const void* x_pdt = d_in[6];
  const int* eidx   = (const int*)d_in[7];
  const void* ew    = d_in[8];
  const void* lp_emb = d_in[9];

  // ---- workspace layout ----
  char* cur = (char*)d_ws;
  auto alloc = [&](size_t bytes, size_t align) -> void* {
    size_t a = ((size_t)cur + align - 1) & ~(align - 1);
    cur = (char*)(a + bytes);
    return (void*)a;
  };
  int* flag     = (int*)alloc(64, 64);
  float* smallW = (float*)alloc(3104 * 4, 16);
  float* f_xw   = (float*)alloc((size_t)NN * DD * 4, 16);
  float* f_deg  = (float*)alloc(NN * 4, 16);
  float* f_dinv = (float*)alloc(NN * 4, 16);
  float* stage  = (float*)alloc(((size_t)NN * DD + 2 * NN) * 4, 16);
  int* counts   = (int*)alloc(NN * 4, 16);
  int* startA   = (int*)alloc((NN + 1) * 4, 16);
  int* cursorE  = (int*)alloc(NN * 4, 16);
  int* bins     = (int*)alloc(128 * 4, 16);
  int* perm_lp  = (int*)alloc(PP * NN * 4, 16);
  int* perm_ns  = (int*)alloc(NN * 4, 16);
  int2* csr2    = (int2*)alloc((size_t)EE * 8, 16);
  u16* ub       = (u16*)alloc((size_t)20233216 * 2, 16);
  u16* embbf_lp = ub;
  u16* embbf_ns = ub + 640000;
  u16* wg_lpih  = ub + 1920000;
  u16* wg_lphh  = ub + 1969152;
  u16* wg_nsih  = ub + 2018304;
  u16* wg_nshh  = ub + 2067456;
  u16* wg_lpfc  = ub + 2116608;
  u16* wg_allfc = ub + 2165760;
  u16* wg_c1    = ub + 2247680;
  u16* wg_c2    = ub + 2264064;
  u16* wg_c3    = ub + 2280448;
  u16* wg_mp1   = ub + 2296832;
  u16* hbf_lp   = ub + 2313216;   // [3N,128]
  u16* hbf_ns   = ub + 9993216;   // [N,128]
  u16* lp_bf    = ub + 12553216;  // [N,128]
  u16* xcur_bf  = ub + 15113216;  // [N,128]
  u16* xw_bf    = ub + 17673216;  // [N,128]
  u16* relu_bf  = hbf_lp;         // dead after lp_fc

  static const int fn[16] = {384, 384, 384, 384, 128, 128, 128, 128,
                             128, 128, 128, 128, 128, 128, 256, 2};
  static const int fsrc[16] = {13, 14, 17, 18, 20, 22, 24, 26,
                               28, 29, 30, 31, 32, 34, 35, 36};
  CvtJobs jf;
  int foff[16];
  {
    int off = 0;
    for (int j = 0; j < 16; ++j) {
      jf.src[j] = d_in[fsrc[j]];
      jf.off[j] = off;
      jf.n[j] = fn[j];
      foff[j] = off;
      off += fn[j];
    }
  }
  float* b_lpbih = smallW + foff[0];
  float* b_lpbhh = smallW + foff[1];
  float* b_nsbih = smallW + foff[2];
  float* b_nsbhh = smallW + foff[3];
  float* b_lpfc  = smallW + foff[4];
  float* b_allfc = smallW + foff[5];
  float* b_conv[3] = {smallW + foff[6], smallW + foff[7], smallW + foff[8]};
  float* g_ln[2] = {smallW + foff[9], smallW + foff[11]};
  float* b_ln[2] = {smallW + foff[10], smallW + foff[12]};
  float* b_mp1   = smallW + foff[13];
  float* w_mp2   = smallW + foff[14];
  float* b_mp2   = smallW + foff[15];

  static const int bn[12] = {640000, 1280000, 49152, 49152, 49152, 49152,
                             49152, 81920, 16384, 16384, 16384, 16384};
  static const int bsrc[12] = {9, 10, 11, 12, 15, 16, 19, 21, 23, 25, 27, 33};
  static const int boff[12] = {0, 640000, 1920000, 1969152, 2018304, 2067456,
                               2116608, 2165760, 2247680, 2264064, 2280448,
                               2296832};
  CvtJobsB jb;
  for (int j = 0; j < 12; ++j) {
    jb.src[j] = d_in[bsrc[j]];
    jb.off[j] = boff[j];
    jb.n[j] = bn[j];
  }

  const int* e_src = eidx;
  const int* e_dst = eidx + EE;

  // 0. dtype detection
  k_detect<<<1, 256, 0, stream>>>(lp_emb, flag);

  // 1. conversions
  k_cvt_batch<<<16, 256, 0, stream>>>(jf, smallW, flag);
  k_cvtb<<<12 * 64, 256, 0, stream>>>(jb, ub, flag);

  // 2. length sorts (ballot-aggregated: ~64x fewer atomics)
  k_zero_i<<<1, 256, 0, stream>>>(bins, 128);
  k_lenhist2<<<(PP * NN + 255) / 256, 256, 0, stream>>>(len_lp, bins, PP * NN, 0, TLP);
  k_lenhist2<<<(NN + 255) / 256, 256, 0, stream>>>(len_ns, bins + 64, NN, 1, TNS);
  k_binscan<<<1, 64, 0, stream>>>(bins, bins + 32, 32);
  k_binscan<<<1, 64, 0, stream>>>(bins + 64, bins + 96, 32);
  k_lenfill2<<<(PP * NN + 255) / 256, 256, 0, stream>>>(len_lp, bins + 32, perm_lp,
                                                        PP * NN, 0, TLP);
  k_lenfill2<<<(NN + 255) / 256, 256, 0, stream>>>(len_ns, bins + 96, perm_ns,
                                                   NN, 1, TNS);

  // 3. degrees + CSR
  k_zero_i<<<(NN + 255) / 256, 256, 0, stream>>>(counts, NN);
  k_hist<<<(EE + 255) / 256, 256, 0, stream>>>(e_dst, counts, EE);
  k_scan<<<1, 256, 0, stream>>>(counts, startA, cursorE, NN);
  k_deg_init<<<(NN + 255) / 256, 256, 0, stream>>>(f_deg, NN);
  k_deg_acc<<<(EE + 255) / 256, 256, 0, stream>>>(e_dst, ew, f_deg, EE, flag);
  k_dinv<<<(NN + 255) / 256, 256, 0, stream>>>(f_deg, f_dinv, NN);
  k_fill2<<<(EE + 255) / 256, 256, 0, stream>>>(e_src, e_dst, ew, cursorE, csr2,
                                                f_dinv, EE, flag);

  // 4. merged GRUs, longest blocks first (NS family leads, descending)
  const int nbLP = PP * NN / 32, nbNS = NN / 32;
  k_gru5<<<nbLP + nbNS, 512, 0, stream>>>(
      perm_lp, perm_ns, nbNS, embbf_lp, embbf_ns, idx_lp, idx_ns, len_lp, len_ns,
      wg_lpih, wg_lphh, wg_nsih, wg_nshh, b_lpbih, b_lpbhh, b_nsbih, b_nsbhh,
      hbf_lp, hbf_ns, nbLP);

  const int gg = (NN + 63) / 64;
  // 5. lp_fc: hbf_lp flat [3N,128] viewed [N,384] == faithful reshape
  k_gemm_mfma<<<gg, 256, 0, stream>>>(hbf_lp, nullptr, nullptr, nullptr, nullptr,
                                      0, 384, wg_lpfc, b_lpfc, lp_bf, 1, NN, flag);
  // 6. all_fc: scramble-gather {pdt, ref, def, lp, ns} -> xcur_bf
  k_gemm_mfma<<<gg, 256, 0, stream>>>(x_pdt, x_ref, x_def, lp_bf, hbf_ns,
                                      1, 640, wg_allfc, b_allfc, xcur_bf, 1, NN, flag);

  // 7. three GCN layers
  const u16* wgc[3] = {wg_c1, wg_c2, wg_c3};
  for (int l = 0; l < 3; ++l) {
    k_gemm_mfma<<<gg, 256, 0, stream>>>(xcur_bf, nullptr, nullptr, nullptr, nullptr,
                                        0, DD, wgc[l], nullptr, xw_bf, 1, NN, flag);
    if (l < 2) {
      k_gcn_gather<<<NN / 4, 256, 0, stream>>>(startA, csr2, f_dinv, xw_bf,
                                               b_conv[l], g_ln[l], b_ln[l],
                                               xcur_bf, nullptr, 0);
    } else {
      k_gcn_gather<<<NN / 4, 256, 0, stream>>>(startA, csr2, f_dinv, xw_bf,
                                               b_conv[l], nullptr, nullptr,
                                               relu_bf, stage, 1);
    }
  }

  // 8. mp head + log_softmax
  k_gemm_mfma<<<gg, 256, 0, stream>>>(relu_bf, nullptr, nullptr, nullptr, nullptr,
                                      0, DD, wg_mp1, b_mp1, f_xw, 0, NN, flag);
  k_mp2_ls<<<(NN + 3) / 4, 256, 0, stream>>>(f_xw, w_mp2, b_mp2,
                                             stage + (size_t)NN * DD, NN);

  // 9. store in detected output dtype
  k_out<<<(out_size + 255) / 256, 256, 0, stream>>>(stage, d_out, out_size, flag);
}